// Round 9
// baseline (559.824 us; speedup 1.0000x reference)
//
#include <hip/hip_runtime.h>

#define FHH 50
#define FWW 84
#define HW 4200
#define NBOX 6000
#define NPAD 6144
#define KKEEP 512
#define WSTRIDE 192   // mask row stride in words (188 used)

typedef float f32x2 __attribute__((ext_vector_type(2)));
typedef float f32x4v __attribute__((ext_vector_type(4)));
typedef _Float16 f16x4 __attribute__((ext_vector_type(4)));
typedef _Float16 f16x2 __attribute__((ext_vector_type(2)));

// output offsets (elements, f32)
#define OFF_BF1  0ULL
#define OFF_BF2  102760448ULL
#define OFF_S1   205520896ULL
#define OFF_S2   205562368ULL
#define OFF_D1   205603840ULL
#define OFF_PROP 205767680ULL
#define OFF_FEAT 205769728ULL

// ---------------- feat transpose [C][H][W] -> [H*W][C] fp16, plus feat copy ----------------
__global__ __launch_bounds__(256) void k_transpose(const float* __restrict__ feat,
                                                   _Float16* __restrict__ featH,
                                                   float* __restrict__ out_feat) {
  __shared__ float t[32][33];
  int hw0 = blockIdx.x * 32;
  int c0  = blockIdx.y * 32;
  int tx = threadIdx.x & 31, ty = threadIdx.x >> 5; // ty 0..7
#pragma unroll
  for (int p = 0; p < 4; ++p) {
    int c = c0 + ty + p * 8;
    int hw = hw0 + tx;
    if (hw < HW) {
      float v = feat[(size_t)c * HW + hw];
      t[ty + p * 8][tx] = v;
      __builtin_nontemporal_store(v, &out_feat[(size_t)c * HW + hw]);
    }
  }
  __syncthreads();
#pragma unroll
  for (int p = 0; p < 4; ++p) {
    int hw = hw0 + ty + p * 8;
    int c = c0 + tx;
    if (hw < HW) featH[((size_t)hw << 10) + c] = (_Float16)t[tx][ty + p * 8];
  }
}

// ---------------- NMS prep: clip, offset, area, sort keys ----------------
__global__ __launch_bounds__(256) void k_prep(const float4* __restrict__ boxes1,
                                              const float4* __restrict__ boxes2,
                                              const float* __restrict__ logits1,
                                              const float* __restrict__ logits2,
                                              const int* __restrict__ levels1,
                                              const int* __restrict__ levels2,
                                              float4* __restrict__ nbox,
                                              float* __restrict__ area,
                                              unsigned long long* __restrict__ keys,
                                              int* __restrict__ rank) {
  int i = blockIdx.x * 256 + threadIdx.x;
  if (i >= NPAD) return;
  if (i >= NBOX) { keys[i] = 0ULL; return; }
  rank[i] = 0;
  float4 b; float sc; int lv;
  if (i < 3000) { b = boxes1[i]; sc = logits1[i]; lv = levels1[i]; }
  else          { b = boxes2[i - 3000]; sc = logits2[i - 3000]; lv = levels2[i - 3000]; }
  // clip (exact: min/max only)
  float x0 = fminf(fmaxf(b.x, 0.f), 1344.f);
  float y0 = fminf(fmaxf(b.y, 0.f), 800.f);
  float x1 = fminf(fmaxf(b.z, 0.f), 1344.f);
  float y1 = fminf(fmaxf(b.w, 0.f), 800.f);
  float off = __fmul_rn((float)lv, 1345.0f);
  x0 = __fadd_rn(x0, off); y0 = __fadd_rn(y0, off);
  x1 = __fadd_rn(x1, off); y1 = __fadd_rn(y1, off);
  nbox[i] = make_float4(x0, y0, x1, y1);
  area[i] = __fmul_rn(__fsub_rn(x1, x0), __fsub_rn(y1, y0));
  unsigned u = __float_as_uint(sc);
  u = (u & 0x80000000u) ? ~u : (u | 0x80000000u);   // order-preserving transform
  keys[i] = ((unsigned long long)u << 32) | (unsigned)(0xFFFFFFFFu - (unsigned)i);
}

// ---------------- rank = #{j : key_j > key_i}  (counting sort, stable desc) ----------------
__global__ __launch_bounds__(256) void k_rank(const unsigned long long* __restrict__ keys,
                                              int* __restrict__ rank) {
  __shared__ unsigned long long ks[1024];
  int jb = blockIdx.y;
  for (int t = threadIdx.x; t < 1024; t += 256) ks[t] = keys[jb * 1024 + t];
  __syncthreads();
  int i = blockIdx.x * 256 + threadIdx.x;
  if (i >= NBOX) return;
  unsigned long long ki = keys[i];
  int c = 0;
  for (int j = 0; j < 1024; ++j) c += (ks[j] > ki) ? 1 : 0;
  if (c) atomicAdd(&rank[i], c);
}

__global__ __launch_bounds__(256) void k_scatter(const float4* __restrict__ nbox,
                                                 const float* __restrict__ area,
                                                 const int* __restrict__ rank,
                                                 float4* __restrict__ sboxes,
                                                 float* __restrict__ sarea,
                                                 int* __restrict__ sorig) {
  int i = blockIdx.x * 256 + threadIdx.x;
  if (i >= NBOX) return;
  int r = rank[i];
  sboxes[r] = nbox[i];
  sarea[r] = area[i];
  sorig[r] = i;
}

// ---------------- suppression bitmask ----------------
__global__ __launch_bounds__(192) void k_mask(const float4* __restrict__ sboxes,
                                              const float* __restrict__ sarea,
                                              unsigned* __restrict__ mask) {
  int i0 = blockIdx.x * 4;
  int w = threadIdx.x;  // 0..191
  float4 b0 = sboxes[i0 + 0], b1 = sboxes[i0 + 1], b2 = sboxes[i0 + 2], b3 = sboxes[i0 + 3];
  float a0 = sarea[i0 + 0], a1 = sarea[i0 + 1], a2 = sarea[i0 + 2], a3 = sarea[i0 + 3];
  unsigned m0 = 0, m1 = 0, m2 = 0, m3 = 0;
  int jbase = w * 32;
  for (int bb = 0; bb < 32; ++bb) {
    int j = jbase + bb;
    if (j >= NBOX) break;
    float4 bj = sboxes[j];
    float aj = sarea[j];
#define IOU_BIT(BR, AR, MR)                                                          \
    {                                                                                \
      float ix0 = fmaxf(BR.x, bj.x), iy0 = fmaxf(BR.y, bj.y);                        \
      float ix1 = fminf(BR.z, bj.z), iy1 = fminf(BR.w, bj.w);                        \
      float iw = fmaxf(__fsub_rn(ix1, ix0), 0.f), ih = fmaxf(__fsub_rn(iy1, iy0), 0.f); \
      float inter = __fmul_rn(iw, ih);                                               \
      float den = __fadd_rn(__fsub_rn(__fadd_rn(AR, aj), inter), 1e-9f);             \
      float iou = __fdiv_rn(inter, den);                                             \
      if (iou > 0.7f) MR |= (1u << bb);                                              \
    }
    IOU_BIT(b0, a0, m0) IOU_BIT(b1, a1, m1) IOU_BIT(b2, a2, m2) IOU_BIT(b3, a3, m3)
#undef IOU_BIT
  }
  mask[(size_t)(i0 + 0) * WSTRIDE + w] = m0;
  mask[(size_t)(i0 + 1) * WSTRIDE + w] = m1;
  mask[(size_t)(i0 + 2) * WSTRIDE + w] = m2;
  mask[(size_t)(i0 + 3) * WSTRIDE + w] = m3;
}

// ---------------- sequential scan, rem bitmap in wave-0 registers ----------------
#define SCAN_CH 64
__global__ __launch_bounds__(256) void k_scan(const unsigned* __restrict__ mask,
                                              const int* __restrict__ sorig,
                                              int* __restrict__ keep) {
  __shared__ unsigned srows[2][SCAN_CH * WSTRIDE];  // 2 x 48 KiB
  __shared__ int s_sorig[2][SCAN_CH];
  __shared__ int s_done, s_kept;
  int tid = threadIdx.x;
  if (tid == 0) { s_done = 0; s_kept = 0; }
  // stage batch 0 with all threads
  for (int idx = tid; idx < SCAN_CH * WSTRIDE; idx += 256) srows[0][idx] = mask[idx];
  if (tid < SCAN_CH) s_sorig[0][tid] = sorig[tid];
  __syncthreads();
  unsigned r0 = 0, r1 = 0, r2 = 0;   // rem words: lane, 64+lane, 128+lane
  int lane = tid;
  int kept = 0;
  for (int g = 0; g < 94; ++g) {
    int cur = g & 1, nxt = cur ^ 1;
    if (tid >= 64) {
      int gn = g + 1;
      if (gn < 94) {
        size_t gbase = (size_t)gn * SCAN_CH * WSTRIDE;
        for (int idx = tid - 64; idx < SCAN_CH * WSTRIDE; idx += 192) {
          size_t gi = gbase + idx;
          srows[nxt][idx] = (gi < (size_t)NBOX * WSTRIDE) ? mask[gi] : 0u;
        }
        if (tid - 64 < SCAN_CH) {
          int i2 = gn * SCAN_CH + (tid - 64);
          s_sorig[nxt][tid - 64] = (i2 < NBOX) ? sorig[i2] : 0;
        }
      }
    } else {
      int base = g * SCAN_CH;
      int nrows = min(SCAN_CH, NBOX - base);
      const unsigned* sb = srows[cur];
      unsigned p0 = sb[lane], p1 = sb[64 + lane], p2 = sb[128 + lane];
      for (int rr = 0; rr < nrows; ++rr) {
        unsigned c0v = p0, c1v = p1, c2v = p2;
        int rn = (rr + 1 < nrows) ? rr + 1 : rr;
        p0 = sb[rn * WSTRIDE + lane];
        p1 = sb[rn * WSTRIDE + 64 + lane];
        p2 = sb[rn * WSTRIDE + 128 + lane];
        int i = base + rr;
        int w = i >> 5, b = i & 31;
        int wl = w & 63, wc = w >> 6;
        unsigned rsel = (wc == 0) ? r0 : ((wc == 1) ? r1 : r2);
        unsigned rw = __shfl(rsel, wl);
        if (!((rw >> b) & 1u)) {
          r0 |= c0v; r1 |= c1v; r2 |= c2v;
          if (lane == 0) keep[kept] = s_sorig[cur][rr];
          kept++;
          if (kept >= KKEEP) break;
        }
      }
      if (lane == 0) { s_kept = kept; if (kept >= KKEEP) s_done = 1; }
    }
    __syncthreads();
    if (s_done) break;
  }
  __syncthreads();
  int fk = s_kept;
  for (int k = fk + tid; k < KKEEP; k += 256) keep[k] = 0;  // ref pads with idx 0
}

// ---------------- proposals + per-(roi,bin) bilinear weights/addresses ----------------
__global__ __launch_bounds__(256) void k_bilin(const int* __restrict__ keep,
                                               const float4* __restrict__ boxes1,
                                               const float4* __restrict__ boxes2,
                                               float4* __restrict__ prop,
                                               float4* __restrict__ bilinW,
                                               int4* __restrict__ bilinA) {
  int r = blockIdx.x;
  __shared__ float4 spb;
  if (threadIdx.x == 0) {
    int o = keep[r];
    float4 b = (o < 3000) ? boxes1[o] : boxes2[o - 3000];
    float4 p = make_float4(fminf(fmaxf(b.x, 0.f), 1344.f),
                           fminf(fmaxf(b.y, 0.f), 800.f),
                           fminf(fmaxf(b.z, 0.f), 1344.f),
                           fminf(fmaxf(b.w, 0.f), 800.f));
    prop[r] = p;
    spb = p;
  }
  __syncthreads();
  int bin = threadIdx.x;
  if (bin >= 196) return;
  float4 pb = spb;
  const float ss = 0.0625f;
  float x0s = pb.x * ss - 0.5f, y0s = pb.y * ss - 0.5f;
  float bw = (pb.z * ss - 0.5f - x0s) / 14.0f;
  float bh = (pb.w * ss - 0.5f - y0s) / 14.0f;
  int py = bin / 14, px = bin - py * 14;
  float xs = x0s + ((float)px + 0.5f) * bw;
  float ys = y0s + ((float)py + 0.5f) * bh;
  float xf = floorf(xs), yf = floorf(ys);
  float lx = xs - xf, ly = ys - yf;
  int ix = (int)xf, iy = (int)yf;
  int x0c = min(max(ix, 0), FWW - 1), x1c = min(max(ix + 1, 0), FWW - 1);
  int y0c = min(max(iy, 0), FHH - 1), y1c = min(max(iy + 1, 0), FHH - 1);
  float wy0 = 1.f - ly, wx0 = 1.f - lx;
  bilinW[r * 196 + bin] = make_float4(wy0 * wx0, wy0 * lx, ly * wx0, ly * lx);
  bilinA[r * 196 + bin] = make_int4((y0c * FWW + x0c) << 10, (y0c * FWW + x1c) << 10,
                                    (y1c * FWW + x0c) << 10, (y1c * FWW + x1c) << 10);
}

// ---------------- phase A: ROIAlign gather -> compact fp16 tile + means ----------------
__global__ __launch_bounds__(256) void k_roiA(const _Float16* __restrict__ featH,
                                              const float4* __restrict__ bilinW,
                                              const int4* __restrict__ bilinA,
                                              const float* __restrict__ scale1,
                                              const float* __restrict__ bias1,
                                              const float* __restrict__ scale2,
                                              const float* __restrict__ bias2,
                                              _Float16* __restrict__ roiT,
                                              float* __restrict__ x1w,
                                              float* __restrict__ x2w) {
  __shared__ _Float16 tile[32 * 200];   // stride 200 (8B-aligned quads)
  __shared__ float part2f[4 * 32];
  __shared__ float sc1[32], bi1[32], sc2[32], bi2[32];
  int bid = blockIdx.x;
  int r = bid & 511;
  int c0 = (bid >> 9) * 32;
  int tid = threadIdx.x;
  int l8 = tid & 7, bg = tid >> 3;       // channel-quad (8), bin-group (32)
  if (tid < 32) {
    sc1[tid] = scale1[c0 + tid]; bi1[tid] = bias1[c0 + tid];
    sc2[tid] = scale2[c0 + tid]; bi2[tid] = bias2[c0 + tid];
  }
  const _Float16* fTb = featH + c0 + l8 * 4;
  const float4* bW = bilinW + r * 196;
  const int4* bA = bilinA + r * 196;
  float4 acc = make_float4(0.f, 0.f, 0.f, 0.f);

#define ROI_BODY(BB)                                                              \
  {                                                                               \
    float4 w = bW[BB]; int4 a = bA[BB];                                           \
    f16x4 g00 = *(const f16x4*)(fTb + a.x);                                       \
    f16x4 g01 = *(const f16x4*)(fTb + a.y);                                       \
    f16x4 g10 = *(const f16x4*)(fTb + a.z);                                       \
    f16x4 g11 = *(const f16x4*)(fTb + a.w);                                       \
    float vx = (float)g00.x * w.x + (float)g01.x * w.y + (float)g10.x * w.z + (float)g11.x * w.w; \
    float vy = (float)g00.y * w.x + (float)g01.y * w.y + (float)g10.y * w.z + (float)g11.y * w.w; \
    float vz = (float)g00.z * w.x + (float)g01.z * w.y + (float)g10.z * w.z + (float)g11.z * w.w; \
    float vw = (float)g00.w * w.x + (float)g01.w * w.y + (float)g10.w * w.z + (float)g11.w * w.w; \
    acc.x += vx; acc.y += vy; acc.z += vz; acc.w += vw;                           \
    int tb = l8 * 800 + (BB);                                                     \
    tile[tb] = (_Float16)vx; tile[tb + 200] = (_Float16)vy;                       \
    tile[tb + 400] = (_Float16)vz; tile[tb + 600] = (_Float16)vw;                 \
  }

  int bb = bg;
#pragma unroll
  for (int i = 0; i < 6; ++i, bb += 32) ROI_BODY(bb)
  if (bg < 4) ROI_BODY(192 + bg)
#undef ROI_BODY

  // reduce acc across the 8 bin-groups within each wave (lanes xor 8, 16, 32)
  acc.x += __shfl_xor(acc.x, 8);  acc.y += __shfl_xor(acc.y, 8);
  acc.z += __shfl_xor(acc.z, 8);  acc.w += __shfl_xor(acc.w, 8);
  acc.x += __shfl_xor(acc.x, 16); acc.y += __shfl_xor(acc.y, 16);
  acc.z += __shfl_xor(acc.z, 16); acc.w += __shfl_xor(acc.w, 16);
  acc.x += __shfl_xor(acc.x, 32); acc.y += __shfl_xor(acc.y, 32);
  acc.z += __shfl_xor(acc.z, 32); acc.w += __shfl_xor(acc.w, 32);
  if ((tid & 63) < 8) {
    int wv = tid >> 6;
    part2f[wv * 32 + l8 * 4 + 0] = acc.x;
    part2f[wv * 32 + l8 * 4 + 1] = acc.y;
    part2f[wv * 32 + l8 * 4 + 2] = acc.z;
    part2f[wv * 32 + l8 * 4 + 3] = acc.w;
  }
  __syncthreads();
  if (tid < 32) {
    float m = ((part2f[tid] + part2f[32 + tid]) + part2f[64 + tid]) + part2f[96 + tid];
    m = m / 196.0f;
    x1w[((size_t)r << 10) + c0 + tid] = m * sc1[tid] + bi1[tid];
    x2w[((size_t)r << 10) + c0 + tid] = m * sc2[tid] + bi2[tid];
  }
  // compact fp16 writeout (plain stores -> stays L3-resident for k_roiB)
  size_t ob = ((size_t)((r << 10) + c0)) * 196;
  _Float16* tp = roiT + ob;
  for (int it = 0; it < 7; ++it) {
    int q = tid + it * 256;
    if (q < 1568) {
      int cl = q / 49;
      int pos = (q - cl * 49) * 4;
      f16x4 h = *(const f16x4*)&tile[cl * 200 + pos];
      *(f16x4*)(tp + 4 * q) = h;
    }
  }
}

// ---------------- phase B: streaming expand roiT -> bf1, bf2 ----------------
// pure stream-copy pattern: linear read, 2x linear NT write.
__global__ __launch_bounds__(256) void k_roiB(const _Float16* __restrict__ roiT,
                                              const float* __restrict__ scale1,
                                              const float* __restrict__ bias1,
                                              const float* __restrict__ scale2,
                                              const float* __restrict__ bias2,
                                              float* __restrict__ bf1,
                                              float* __restrict__ bf2) {
  size_t base = (size_t)blockIdx.x * 12544;   // quads (12544 = 49*256)
  int cbase = blockIdx.x * 256;               // base/49, exact
  int tid = threadIdx.x;
  for (int it = 0; it < 49; ++it) {
    int qib = tid + it * 256;
    size_t Q = base + qib;
    f16x4 h = *(const f16x4*)(roiT + 4 * Q);
    int c = (cbase + qib / 49) & 1023;
    float s1v = scale1[c], b1v = bias1[c], s2v = scale2[c], b2v = bias2[c];
    float v0 = (float)h.x, v1 = (float)h.y, v2 = (float)h.z, v3 = (float)h.w;
    f32x4v o1 = { v0 * s1v + b1v, v1 * s1v + b1v, v2 * s1v + b1v, v3 * s1v + b1v };
    f32x4v o2 = { v0 * s2v + b2v, v1 * s2v + b2v, v2 * s2v + b2v, v3 * s2v + b2v };
    __builtin_nontemporal_store(o1, (f32x4v*)(bf1 + 4 * Q));
    __builtin_nontemporal_store(o2, (f32x4v*)(bf2 + 4 * Q));
  }
}

// ---------------- fallback: fused k_roi (Round-7 best) ----------------
__global__ __launch_bounds__(256) void k_roi(const _Float16* __restrict__ featH,
                                             const float4* __restrict__ bilinW,
                                             const int4* __restrict__ bilinA,
                                             const float* __restrict__ scale1,
                                             const float* __restrict__ bias1,
                                             const float* __restrict__ scale2,
                                             const float* __restrict__ bias2,
                                             float* __restrict__ bf1,
                                             float* __restrict__ bf2,
                                             float* __restrict__ x1w,
                                             float* __restrict__ x2w) {
  __shared__ _Float16 tile[32 * 198];
  __shared__ float part2f[4 * 32];
  __shared__ float sc1[32], bi1[32], sc2[32], bi2[32];
  int bid = blockIdx.x;
  int r = bid & 511;
  int c0 = (bid >> 9) * 32;
  int tid = threadIdx.x;
  int l8 = tid & 7, bg = tid >> 3;
  if (tid < 32) {
    sc1[tid] = scale1[c0 + tid]; bi1[tid] = bias1[c0 + tid];
    sc2[tid] = scale2[c0 + tid]; bi2[tid] = bias2[c0 + tid];
  }
  const _Float16* fTb = featH + c0 + l8 * 4;
  const float4* bW = bilinW + r * 196;
  const int4* bA = bilinA + r * 196;
  float4 acc = make_float4(0.f, 0.f, 0.f, 0.f);
#define ROI_BODY(BB)                                                              \
  {                                                                               \
    float4 w = bW[BB]; int4 a = bA[BB];                                           \
    f16x4 g00 = *(const f16x4*)(fTb + a.x);                                       \
    f16x4 g01 = *(const f16x4*)(fTb + a.y);                                       \
    f16x4 g10 = *(const f16x4*)(fTb + a.z);                                       \
    f16x4 g11 = *(const f16x4*)(fTb + a.w);                                       \
    float vx = (float)g00.x * w.x + (float)g01.x * w.y + (float)g10.x * w.z + (float)g11.x * w.w; \
    float vy = (float)g00.y * w.x + (float)g01.y * w.y + (float)g10.y * w.z + (float)g11.y * w.w; \
    float vz = (float)g00.z * w.x + (float)g01.z * w.y + (float)g10.z * w.z + (float)g11.z * w.w; \
    float vw = (float)g00.w * w.x + (float)g01.w * w.y + (float)g10.w * w.z + (float)g11.w * w.w; \
    acc.x += vx; acc.y += vy; acc.z += vz; acc.w += vw;                           \
    int tb = l8 * 792 + (BB);                                                     \
    tile[tb] = (_Float16)vx; tile[tb + 198] = (_Float16)vy;                       \
    tile[tb + 396] = (_Float16)vz; tile[tb + 594] = (_Float16)vw;                 \
  }
  int bb = bg;
#pragma unroll
  for (int i = 0; i < 6; ++i, bb += 32) ROI_BODY(bb)
  if (bg < 4) ROI_BODY(192 + bg)
#undef ROI_BODY
  acc.x += __shfl_xor(acc.x, 8);  acc.y += __shfl_xor(acc.y, 8);
  acc.z += __shfl_xor(acc.z, 8);  acc.w += __shfl_xor(acc.w, 8);
  acc.x += __shfl_xor(acc.x, 16); acc.y += __shfl_xor(acc.y, 16);
  acc.z += __shfl_xor(acc.z, 16); acc.w += __shfl_xor(acc.w, 16);
  acc.x += __shfl_xor(acc.x, 32); acc.y += __shfl_xor(acc.y, 32);
  acc.z += __shfl_xor(acc.z, 32); acc.w += __shfl_xor(acc.w, 32);
  if ((tid & 63) < 8) {
    int wv = tid >> 6;
    part2f[wv * 32 + l8 * 4 + 0] = acc.x;
    part2f[wv * 32 + l8 * 4 + 1] = acc.y;
    part2f[wv * 32 + l8 * 4 + 2] = acc.z;
    part2f[wv * 32 + l8 * 4 + 3] = acc.w;
  }
  __syncthreads();
  if (tid < 32) {
    float m = ((part2f[tid] + part2f[32 + tid]) + part2f[64 + tid]) + part2f[96 + tid];
    m = m / 196.0f;
    x1w[((size_t)r << 10) + c0 + tid] = m * sc1[tid] + bi1[tid];
    x2w[((size_t)r << 10) + c0 + tid] = m * sc2[tid] + bi2[tid];
  }
  size_t ob = ((size_t)((r << 10) + c0)) * 196;
  float* b1p = bf1 + ob;
  float* b2p = bf2 + ob;
  for (int it = 0; it < 13; ++it) {
    int f2 = tid + it * 256;
    if (f2 < 3136) {
      int cl = (int)((unsigned)f2 / 98u);
      int pr = f2 - cl * 98;
      f16x2 h = *(const f16x2*)&tile[cl * 198 + 2 * pr];
      float v0 = (float)h.x, v1 = (float)h.y;
      float s1v = sc1[cl], b1v = bi1[cl], s2v = sc2[cl], b2v = bi2[cl];
      f32x2 o1 = { v0 * s1v + b1v, v1 * s1v + b1v };
      f32x2 o2 = { v0 * s2v + b2v, v1 * s2v + b2v };
      __builtin_nontemporal_store(o1, (f32x2*)(b1p + 2 * f2));
      __builtin_nontemporal_store(o2, (f32x2*)(b2p + 2 * f2));
    }
  }
}

// ---------------- small GEMMs: s1 = x1@Wc1+bc1, d1 = x1@Wb1+bb1, s2 = x2@Wc2+bc2 ----------------
__global__ __launch_bounds__(256) void k_gemm(const float* __restrict__ x1,
                                              const float* __restrict__ x2,
                                              const float* __restrict__ Wc1, const float* __restrict__ bc1,
                                              const float* __restrict__ Wb1, const float* __restrict__ bb1,
                                              const float* __restrict__ Wc2, const float* __restrict__ bc2,
                                              float* __restrict__ s1, float* __restrict__ d1,
                                              float* __restrict__ s2) {
  int z = blockIdx.z;
  const float* A; const float* W; const float* bias; float* out; int N;
  if (z == 0)      { A = x1; W = Wc1; bias = bc1; out = s1; N = 81; }
  else if (z == 1) { A = x1; W = Wb1; bias = bb1; out = d1; N = 320; }
  else             { A = x2; W = Wc2; bias = bc2; out = s2; N = 81; }
  int n0 = blockIdx.y * 32;
  if (n0 >= N) return;
  int m0 = blockIdx.x * 32;
  __shared__ float As[32][34];
  __shared__ float Bs[32][34];
  int tid = threadIdx.x;
  int tx = tid & 15, ty = tid >> 4;
  float acc00 = 0, acc01 = 0, acc10 = 0, acc11 = 0;
  for (int k0 = 0; k0 < 1024; k0 += 32) {
    int mm = tid >> 3, g = tid & 7;
    float4 av = *(const float4*)(A + (size_t)(m0 + mm) * 1024 + k0 + g * 4);
    As[g * 4 + 0][mm] = av.x; As[g * 4 + 1][mm] = av.y;
    As[g * 4 + 2][mm] = av.z; As[g * 4 + 3][mm] = av.w;
    int nn = tid & 31, kh = tid >> 5;
#pragma unroll
    for (int qq = 0; qq < 4; ++qq) {
      int kk = kh + 8 * qq;
      int n = n0 + nn;
      Bs[kk][nn] = (n < N) ? W[(size_t)(k0 + kk) * N + n] : 0.f;
    }
    __syncthreads();
#pragma unroll
    for (int kk = 0; kk < 32; ++kk) {
      float2 a = *(const float2*)&As[kk][2 * ty];
      float2 b = *(const float2*)&Bs[kk][2 * tx];
      acc00 += a.x * b.x; acc01 += a.x * b.y;
      acc10 += a.y * b.x; acc11 += a.y * b.y;
    }
    __syncthreads();
  }
  int m = m0 + 2 * ty, n = n0 + 2 * tx;
  if (n < N) {
    out[(size_t)m * N + n] = acc00 + bias[n];
    out[(size_t)(m + 1) * N + n] = acc10 + bias[n];
  }
  if (n + 1 < N) {
    out[(size_t)m * N + n + 1] = acc01 + bias[n + 1];
    out[(size_t)(m + 1) * N + n + 1] = acc11 + bias[n + 1];
  }
}

extern "C" void kernel_launch(void* const* d_in, const int* in_sizes, int n_in,
                              void* d_out, int out_size, void* d_ws, size_t ws_size,
                              hipStream_t stream) {
  (void)in_sizes; (void)n_in; (void)out_size;
  const float* feat    = (const float*)d_in[0];
  const float4* boxes1 = (const float4*)d_in[1];
  const float4* boxes2 = (const float4*)d_in[2];
  const float* logits1 = (const float*)d_in[3];
  const float* logits2 = (const float*)d_in[4];
  const int* levels1   = (const int*)d_in[5];
  const int* levels2   = (const int*)d_in[6];
  const float* scale1  = (const float*)d_in[7];
  const float* bias1   = (const float*)d_in[8];
  const float* scale2  = (const float*)d_in[9];
  const float* bias2   = (const float*)d_in[10];
  const float* W_cls1  = (const float*)d_in[11];
  const float* b_cls1  = (const float*)d_in[12];
  const float* W_box1  = (const float*)d_in[13];
  const float* b_box1  = (const float*)d_in[14];
  const float* W_cls2  = (const float*)d_in[15];
  const float* b_cls2  = (const float*)d_in[16];

  float* out = (float*)d_out;
  char* w = (char*)d_ws;
  _Float16* featH           = (_Float16*)(w + 0);                // 8,601,600 B used
  unsigned long long* keys  = (unsigned long long*)(w + 17203200);
  float4* nbox              = (float4*)(w + 17252352);
  float* area               = (float*)(w + 17348352);
  int* rank                 = (int*)(w + 17372352);
  float4* sboxes            = (float4*)(w + 17396352);
  float* sarea              = (float*)(w + 17492352);
  int* sorig                = (int*)(w + 17516352);
  unsigned* mask            = (unsigned*)(w + 17540352);
  int* keep                 = (int*)(w + 22148352);
  float* x1w                = (float*)(w + 22150400);
  float* x2w                = (float*)(w + 24247552);
  // bilin tables alias the (dead-by-then) mask region
  float4* bilinW            = (float4*)(w + 17540352);           // 1,605,632 B
  int4* bilinA              = (int4*)(w + 19145984);             // 1,605,632 B (< keep @22148352)
  _Float16* roiT            = (_Float16*)(w + 26344704);         // 205,520,896 B (needs big ws)
  const size_t WS_NEEDED = 26344704ULL + 205520896ULL;

  k_transpose<<<dim3(132, 32), 256, 0, stream>>>(feat, featH, out + OFF_FEAT);
  k_prep<<<24, 256, 0, stream>>>(boxes1, boxes2, logits1, logits2, levels1, levels2,
                                 nbox, area, keys, rank);
  k_rank<<<dim3(24, 6), 256, 0, stream>>>(keys, rank);
  k_scatter<<<24, 256, 0, stream>>>(nbox, area, rank, sboxes, sarea, sorig);
  k_mask<<<1500, 192, 0, stream>>>(sboxes, sarea, mask);
  k_scan<<<1, 256, 0, stream>>>(mask, sorig, keep);
  k_bilin<<<512, 256, 0, stream>>>(keep, boxes1, boxes2,
                                   (float4*)(out + OFF_PROP), bilinW, bilinA);
  if (ws_size >= WS_NEEDED) {
    k_roiA<<<16384, 256, 0, stream>>>(featH, bilinW, bilinA,
                                      scale1, bias1, scale2, bias2,
                                      roiT, x1w, x2w);
    k_roiB<<<2048, 256, 0, stream>>>(roiT, scale1, bias1, scale2, bias2,
                                     out + OFF_BF1, out + OFF_BF2);
  } else {
    k_roi<<<16384, 256, 0, stream>>>(featH, bilinW, bilinA,
                                     scale1, bias1, scale2, bias2,
                                     out + OFF_BF1, out + OFF_BF2, x1w, x2w);
  }
  k_gemm<<<dim3(16, 10, 3), 256, 0, stream>>>(x1w, x2w, W_cls1, b_cls1, W_box1, b_box1,
                                              W_cls2, b_cls2,
                                              out + OFF_S1, out + OFF_D1, out + OFF_S2);
}

// Round 10
// 475.581 us; speedup vs baseline: 1.1771x; 1.1771x over previous
//
#include <hip/hip_runtime.h>

#define FHH 50
#define FWW 84
#define HW 4200
#define NBOX 6000
#define NPAD 6144
#define KKEEP 512
#define WSTRIDE 192   // mask row stride in words (188 used)

typedef float f32x2 __attribute__((ext_vector_type(2)));
typedef float f32x4v __attribute__((ext_vector_type(4)));
typedef _Float16 f16x4 __attribute__((ext_vector_type(4)));
typedef _Float16 f16x2 __attribute__((ext_vector_type(2)));

// output offsets (elements, f32)
#define OFF_BF1  0ULL
#define OFF_BF2  102760448ULL
#define OFF_S1   205520896ULL
#define OFF_S2   205562368ULL
#define OFF_D1   205603840ULL
#define OFF_PROP 205767680ULL
#define OFF_FEAT 205769728ULL

// ---------------- feat transpose [C][H][W] -> [H*W][C] fp16, plus feat copy ----------------
__global__ __launch_bounds__(256) void k_transpose(const float* __restrict__ feat,
                                                   _Float16* __restrict__ featH,
                                                   float* __restrict__ out_feat) {
  __shared__ float t[32][33];
  int hw0 = blockIdx.x * 32;
  int c0  = blockIdx.y * 32;
  int tx = threadIdx.x & 31, ty = threadIdx.x >> 5; // ty 0..7
#pragma unroll
  for (int p = 0; p < 4; ++p) {
    int c = c0 + ty + p * 8;
    int hw = hw0 + tx;
    if (hw < HW) {
      float v = feat[(size_t)c * HW + hw];
      t[ty + p * 8][tx] = v;
      __builtin_nontemporal_store(v, &out_feat[(size_t)c * HW + hw]);
    }
  }
  __syncthreads();
#pragma unroll
  for (int p = 0; p < 4; ++p) {
    int hw = hw0 + ty + p * 8;
    int c = c0 + tx;
    if (hw < HW) featH[((size_t)hw << 10) + c] = (_Float16)t[tx][ty + p * 8];
  }
}

// ---------------- NMS prep: clip, offset, area, sort keys ----------------
__global__ __launch_bounds__(256) void k_prep(const float4* __restrict__ boxes1,
                                              const float4* __restrict__ boxes2,
                                              const float* __restrict__ logits1,
                                              const float* __restrict__ logits2,
                                              const int* __restrict__ levels1,
                                              const int* __restrict__ levels2,
                                              float4* __restrict__ nbox,
                                              float* __restrict__ area,
                                              unsigned long long* __restrict__ keys,
                                              int* __restrict__ rank) {
  int i = blockIdx.x * 256 + threadIdx.x;
  if (i >= NPAD) return;
  if (i >= NBOX) { keys[i] = 0ULL; return; }
  rank[i] = 0;
  float4 b; float sc; int lv;
  if (i < 3000) { b = boxes1[i]; sc = logits1[i]; lv = levels1[i]; }
  else          { b = boxes2[i - 3000]; sc = logits2[i - 3000]; lv = levels2[i - 3000]; }
  // clip (exact: min/max only)
  float x0 = fminf(fmaxf(b.x, 0.f), 1344.f);
  float y0 = fminf(fmaxf(b.y, 0.f), 800.f);
  float x1 = fminf(fmaxf(b.z, 0.f), 1344.f);
  float y1 = fminf(fmaxf(b.w, 0.f), 800.f);
  float off = __fmul_rn((float)lv, 1345.0f);
  x0 = __fadd_rn(x0, off); y0 = __fadd_rn(y0, off);
  x1 = __fadd_rn(x1, off); y1 = __fadd_rn(y1, off);
  nbox[i] = make_float4(x0, y0, x1, y1);
  area[i] = __fmul_rn(__fsub_rn(x1, x0), __fsub_rn(y1, y0));
  unsigned u = __float_as_uint(sc);
  u = (u & 0x80000000u) ? ~u : (u | 0x80000000u);   // order-preserving transform
  keys[i] = ((unsigned long long)u << 32) | (unsigned)(0xFFFFFFFFu - (unsigned)i);
}

// ---------------- rank = #{j : key_j > key_i}  (counting sort, stable desc) ----------------
__global__ __launch_bounds__(256) void k_rank(const unsigned long long* __restrict__ keys,
                                              int* __restrict__ rank) {
  __shared__ unsigned long long ks[1024];
  int jb = blockIdx.y;
  for (int t = threadIdx.x; t < 1024; t += 256) ks[t] = keys[jb * 1024 + t];
  __syncthreads();
  int i = blockIdx.x * 256 + threadIdx.x;
  if (i >= NBOX) return;
  unsigned long long ki = keys[i];
  int c = 0;
  for (int j = 0; j < 1024; ++j) c += (ks[j] > ki) ? 1 : 0;
  if (c) atomicAdd(&rank[i], c);
}

__global__ __launch_bounds__(256) void k_scatter(const float4* __restrict__ nbox,
                                                 const float* __restrict__ area,
                                                 const int* __restrict__ rank,
                                                 float4* __restrict__ sboxes,
                                                 float* __restrict__ sarea,
                                                 int* __restrict__ sorig) {
  int i = blockIdx.x * 256 + threadIdx.x;
  if (i >= NBOX) return;
  int r = rank[i];
  sboxes[r] = nbox[i];
  sarea[r] = area[i];
  sorig[r] = i;
}

// ---------------- suppression bitmask ----------------
__global__ __launch_bounds__(192) void k_mask(const float4* __restrict__ sboxes,
                                              const float* __restrict__ sarea,
                                              unsigned* __restrict__ mask) {
  int i0 = blockIdx.x * 4;
  int w = threadIdx.x;  // 0..191
  float4 b0 = sboxes[i0 + 0], b1 = sboxes[i0 + 1], b2 = sboxes[i0 + 2], b3 = sboxes[i0 + 3];
  float a0 = sarea[i0 + 0], a1 = sarea[i0 + 1], a2 = sarea[i0 + 2], a3 = sarea[i0 + 3];
  unsigned m0 = 0, m1 = 0, m2 = 0, m3 = 0;
  int jbase = w * 32;
  for (int bb = 0; bb < 32; ++bb) {
    int j = jbase + bb;
    if (j >= NBOX) break;
    float4 bj = sboxes[j];
    float aj = sarea[j];
#define IOU_BIT(BR, AR, MR)                                                          \
    {                                                                                \
      float ix0 = fmaxf(BR.x, bj.x), iy0 = fmaxf(BR.y, bj.y);                        \
      float ix1 = fminf(BR.z, bj.z), iy1 = fminf(BR.w, bj.w);                        \
      float iw = fmaxf(__fsub_rn(ix1, ix0), 0.f), ih = fmaxf(__fsub_rn(iy1, iy0), 0.f); \
      float inter = __fmul_rn(iw, ih);                                               \
      float den = __fadd_rn(__fsub_rn(__fadd_rn(AR, aj), inter), 1e-9f);             \
      float iou = __fdiv_rn(inter, den);                                             \
      if (iou > 0.7f) MR |= (1u << bb);                                              \
    }
    IOU_BIT(b0, a0, m0) IOU_BIT(b1, a1, m1) IOU_BIT(b2, a2, m2) IOU_BIT(b3, a3, m3)
#undef IOU_BIT
  }
  mask[(size_t)(i0 + 0) * WSTRIDE + w] = m0;
  mask[(size_t)(i0 + 1) * WSTRIDE + w] = m1;
  mask[(size_t)(i0 + 2) * WSTRIDE + w] = m2;
  mask[(size_t)(i0 + 3) * WSTRIDE + w] = m3;
}

// ---------------- sequential scan, rem bitmap in wave-0 registers ----------------
#define SCAN_CH 64
__global__ __launch_bounds__(256) void k_scan(const unsigned* __restrict__ mask,
                                              const int* __restrict__ sorig,
                                              int* __restrict__ keep) {
  __shared__ unsigned srows[2][SCAN_CH * WSTRIDE];  // 2 x 48 KiB
  __shared__ int s_sorig[2][SCAN_CH];
  __shared__ int s_done, s_kept;
  int tid = threadIdx.x;
  if (tid == 0) { s_done = 0; s_kept = 0; }
  // stage batch 0 with all threads
  for (int idx = tid; idx < SCAN_CH * WSTRIDE; idx += 256) srows[0][idx] = mask[idx];
  if (tid < SCAN_CH) s_sorig[0][tid] = sorig[tid];
  __syncthreads();
  unsigned r0 = 0, r1 = 0, r2 = 0;   // rem words: lane, 64+lane, 128+lane
  int lane = tid;
  int kept = 0;
  for (int g = 0; g < 94; ++g) {
    int cur = g & 1, nxt = cur ^ 1;
    if (tid >= 64) {
      int gn = g + 1;
      if (gn < 94) {
        size_t gbase = (size_t)gn * SCAN_CH * WSTRIDE;
        for (int idx = tid - 64; idx < SCAN_CH * WSTRIDE; idx += 192) {
          size_t gi = gbase + idx;
          srows[nxt][idx] = (gi < (size_t)NBOX * WSTRIDE) ? mask[gi] : 0u;
        }
        if (tid - 64 < SCAN_CH) {
          int i2 = gn * SCAN_CH + (tid - 64);
          s_sorig[nxt][tid - 64] = (i2 < NBOX) ? sorig[i2] : 0;
        }
      }
    } else {
      int base = g * SCAN_CH;
      int nrows = min(SCAN_CH, NBOX - base);
      const unsigned* sb = srows[cur];
      unsigned p0 = sb[lane], p1 = sb[64 + lane], p2 = sb[128 + lane];
      for (int rr = 0; rr < nrows; ++rr) {
        unsigned c0v = p0, c1v = p1, c2v = p2;
        int rn = (rr + 1 < nrows) ? rr + 1 : rr;
        p0 = sb[rn * WSTRIDE + lane];
        p1 = sb[rn * WSTRIDE + 64 + lane];
        p2 = sb[rn * WSTRIDE + 128 + lane];
        int i = base + rr;
        int w = i >> 5, b = i & 31;
        int wl = w & 63, wc = w >> 6;
        unsigned rsel = (wc == 0) ? r0 : ((wc == 1) ? r1 : r2);
        unsigned rw = __shfl(rsel, wl);
        if (!((rw >> b) & 1u)) {
          r0 |= c0v; r1 |= c1v; r2 |= c2v;
          if (lane == 0) keep[kept] = s_sorig[cur][rr];
          kept++;
          if (kept >= KKEEP) break;
        }
      }
      if (lane == 0) { s_kept = kept; if (kept >= KKEEP) s_done = 1; }
    }
    __syncthreads();
    if (s_done) break;
  }
  __syncthreads();
  int fk = s_kept;
  for (int k = fk + tid; k < KKEEP; k += 256) keep[k] = 0;  // ref pads with idx 0
}

// ---------------- proposals + per-(roi,bin) bilinear weights/addresses ----------------
__global__ __launch_bounds__(256) void k_bilin(const int* __restrict__ keep,
                                               const float4* __restrict__ boxes1,
                                               const float4* __restrict__ boxes2,
                                               float4* __restrict__ prop,
                                               float4* __restrict__ bilinW,
                                               int4* __restrict__ bilinA) {
  int r = blockIdx.x;
  __shared__ float4 spb;
  if (threadIdx.x == 0) {
    int o = keep[r];
    float4 b = (o < 3000) ? boxes1[o] : boxes2[o - 3000];
    float4 p = make_float4(fminf(fmaxf(b.x, 0.f), 1344.f),
                           fminf(fmaxf(b.y, 0.f), 800.f),
                           fminf(fmaxf(b.z, 0.f), 1344.f),
                           fminf(fmaxf(b.w, 0.f), 800.f));
    prop[r] = p;
    spb = p;
  }
  __syncthreads();
  int bin = threadIdx.x;
  if (bin >= 196) return;
  float4 pb = spb;
  const float ss = 0.0625f;
  float x0s = pb.x * ss - 0.5f, y0s = pb.y * ss - 0.5f;
  float bw = (pb.z * ss - 0.5f - x0s) / 14.0f;
  float bh = (pb.w * ss - 0.5f - y0s) / 14.0f;
  int py = bin / 14, px = bin - py * 14;
  float xs = x0s + ((float)px + 0.5f) * bw;
  float ys = y0s + ((float)py + 0.5f) * bh;
  float xf = floorf(xs), yf = floorf(ys);
  float lx = xs - xf, ly = ys - yf;
  int ix = (int)xf, iy = (int)yf;
  int x0c = min(max(ix, 0), FWW - 1), x1c = min(max(ix + 1, 0), FWW - 1);
  int y0c = min(max(iy, 0), FHH - 1), y1c = min(max(iy + 1, 0), FHH - 1);
  float wy0 = 1.f - ly, wx0 = 1.f - lx;
  bilinW[r * 196 + bin] = make_float4(wy0 * wx0, wy0 * lx, ly * wx0, ly * lx);
  bilinA[r * 196 + bin] = make_int4((y0c * FWW + x0c) << 10, (y0c * FWW + x1c) << 10,
                                    (y1c * FWW + x0c) << 10, (y1c * FWW + x1c) << 10);
}

// ---------------- ROIAlign + both affine heads + fused mean -> x1,x2 ----------------
// Round-10 change: writeout is PHASED — all bf1 quads first, then all bf2 quads,
// so each wave emits ONE monotonic NT store stream at a time (fill-like pattern).
__global__ __launch_bounds__(256) void k_roi(const _Float16* __restrict__ featH,
                                             const float4* __restrict__ bilinW,
                                             const int4* __restrict__ bilinA,
                                             const float* __restrict__ scale1,
                                             const float* __restrict__ bias1,
                                             const float* __restrict__ scale2,
                                             const float* __restrict__ bias2,
                                             float* __restrict__ bf1,
                                             float* __restrict__ bf2,
                                             float* __restrict__ x1w,
                                             float* __restrict__ x2w) {
  __shared__ _Float16 tile[32 * 200];   // 12800 B, stride 200 (16B-aligned quads)
  __shared__ float part2f[4 * 32];
  __shared__ float sc1[32], bi1[32], sc2[32], bi2[32];
  int bid = blockIdx.x;
  int r = bid & 511;
  int c0 = (bid >> 9) * 32;
  int tid = threadIdx.x;
  int l8 = tid & 7, bg = tid >> 3;       // channel-quad (8), bin-group (32)
  if (tid < 32) {
    sc1[tid] = scale1[c0 + tid]; bi1[tid] = bias1[c0 + tid];
    sc2[tid] = scale2[c0 + tid]; bi2[tid] = bias2[c0 + tid];
  }
  const _Float16* fTb = featH + c0 + l8 * 4;
  const float4* bW = bilinW + r * 196;
  const int4* bA = bilinA + r * 196;
  float4 acc = make_float4(0.f, 0.f, 0.f, 0.f);

#define ROI_BODY(BB)                                                              \
  {                                                                               \
    float4 w = bW[BB]; int4 a = bA[BB];                                           \
    f16x4 g00 = *(const f16x4*)(fTb + a.x);                                       \
    f16x4 g01 = *(const f16x4*)(fTb + a.y);                                       \
    f16x4 g10 = *(const f16x4*)(fTb + a.z);                                       \
    f16x4 g11 = *(const f16x4*)(fTb + a.w);                                       \
    float vx = (float)g00.x * w.x + (float)g01.x * w.y + (float)g10.x * w.z + (float)g11.x * w.w; \
    float vy = (float)g00.y * w.x + (float)g01.y * w.y + (float)g10.y * w.z + (float)g11.y * w.w; \
    float vz = (float)g00.z * w.x + (float)g01.z * w.y + (float)g10.z * w.z + (float)g11.z * w.w; \
    float vw = (float)g00.w * w.x + (float)g01.w * w.y + (float)g10.w * w.z + (float)g11.w * w.w; \
    acc.x += vx; acc.y += vy; acc.z += vz; acc.w += vw;                           \
    int tb = l8 * 800 + (BB);                                                     \
    tile[tb] = (_Float16)vx; tile[tb + 200] = (_Float16)vy;                       \
    tile[tb + 400] = (_Float16)vz; tile[tb + 600] = (_Float16)vw;                 \
  }

  int bb = bg;
#pragma unroll
  for (int i = 0; i < 6; ++i, bb += 32) ROI_BODY(bb)
  if (bg < 4) ROI_BODY(192 + bg)
#undef ROI_BODY

  // reduce acc across the 8 bin-groups within each wave (lanes xor 8, 16, 32)
  acc.x += __shfl_xor(acc.x, 8);  acc.y += __shfl_xor(acc.y, 8);
  acc.z += __shfl_xor(acc.z, 8);  acc.w += __shfl_xor(acc.w, 8);
  acc.x += __shfl_xor(acc.x, 16); acc.y += __shfl_xor(acc.y, 16);
  acc.z += __shfl_xor(acc.z, 16); acc.w += __shfl_xor(acc.w, 16);
  acc.x += __shfl_xor(acc.x, 32); acc.y += __shfl_xor(acc.y, 32);
  acc.z += __shfl_xor(acc.z, 32); acc.w += __shfl_xor(acc.w, 32);
  if ((tid & 63) < 8) {
    int wv = tid >> 6;
    part2f[wv * 32 + l8 * 4 + 0] = acc.x;
    part2f[wv * 32 + l8 * 4 + 1] = acc.y;
    part2f[wv * 32 + l8 * 4 + 2] = acc.z;
    part2f[wv * 32 + l8 * 4 + 3] = acc.w;
  }
  __syncthreads();
  if (tid < 32) {
    float m = ((part2f[tid] + part2f[32 + tid]) + part2f[64 + tid]) + part2f[96 + tid];
    m = m / 196.0f;
    x1w[((size_t)r << 10) + c0 + tid] = m * sc1[tid] + bi1[tid];
    x2w[((size_t)r << 10) + c0 + tid] = m * sc2[tid] + bi2[tid];
  }
  size_t ob = ((size_t)((r << 10) + c0)) * 196;
  // phase 1: bf1 only — one monotonic NT stream per wave
  {
    float* b1p = bf1 + ob;
#pragma unroll
    for (int it = 0; it < 7; ++it) {
      int q = tid + it * 256;
      if (q < 1568) {
        int cl = q / 49;
        int pos = (q - cl * 49) * 4;
        f16x4 h = *(const f16x4*)&tile[cl * 200 + pos];
        float s1v = sc1[cl], b1v = bi1[cl];
        f32x4v o1 = { (float)h.x * s1v + b1v, (float)h.y * s1v + b1v,
                      (float)h.z * s1v + b1v, (float)h.w * s1v + b1v };
        __builtin_nontemporal_store(o1, (f32x4v*)(b1p + 4 * q));
      }
    }
  }
  // phase 2: bf2 only
  {
    float* b2p = bf2 + ob;
#pragma unroll
    for (int it = 0; it < 7; ++it) {
      int q = tid + it * 256;
      if (q < 1568) {
        int cl = q / 49;
        int pos = (q - cl * 49) * 4;
        f16x4 h = *(const f16x4*)&tile[cl * 200 + pos];
        float s2v = sc2[cl], b2v = bi2[cl];
        f32x4v o2 = { (float)h.x * s2v + b2v, (float)h.y * s2v + b2v,
                      (float)h.z * s2v + b2v, (float)h.w * s2v + b2v };
        __builtin_nontemporal_store(o2, (f32x4v*)(b2p + 4 * q));
      }
    }
  }
}

// ---------------- small GEMMs: s1 = x1@Wc1+bc1, d1 = x1@Wb1+bb1, s2 = x2@Wc2+bc2 ----------------
__global__ __launch_bounds__(256) void k_gemm(const float* __restrict__ x1,
                                              const float* __restrict__ x2,
                                              const float* __restrict__ Wc1, const float* __restrict__ bc1,
                                              const float* __restrict__ Wb1, const float* __restrict__ bb1,
                                              const float* __restrict__ Wc2, const float* __restrict__ bc2,
                                              float* __restrict__ s1, float* __restrict__ d1,
                                              float* __restrict__ s2) {
  int z = blockIdx.z;
  const float* A; const float* W; const float* bias; float* out; int N;
  if (z == 0)      { A = x1; W = Wc1; bias = bc1; out = s1; N = 81; }
  else if (z == 1) { A = x1; W = Wb1; bias = bb1; out = d1; N = 320; }
  else             { A = x2; W = Wc2; bias = bc2; out = s2; N = 81; }
  int n0 = blockIdx.y * 32;
  if (n0 >= N) return;
  int m0 = blockIdx.x * 32;
  __shared__ float As[32][34];
  __shared__ float Bs[32][34];
  int tid = threadIdx.x;
  int tx = tid & 15, ty = tid >> 4;
  float acc00 = 0, acc01 = 0, acc10 = 0, acc11 = 0;
  for (int k0 = 0; k0 < 1024; k0 += 32) {
    int mm = tid >> 3, g = tid & 7;
    float4 av = *(const float4*)(A + (size_t)(m0 + mm) * 1024 + k0 + g * 4);
    As[g * 4 + 0][mm] = av.x; As[g * 4 + 1][mm] = av.y;
    As[g * 4 + 2][mm] = av.z; As[g * 4 + 3][mm] = av.w;
    int nn = tid & 31, kh = tid >> 5;
#pragma unroll
    for (int qq = 0; qq < 4; ++qq) {
      int kk = kh + 8 * qq;
      int n = n0 + nn;
      Bs[kk][nn] = (n < N) ? W[(size_t)(k0 + kk) * N + n] : 0.f;
    }
    __syncthreads();
#pragma unroll
    for (int kk = 0; kk < 32; ++kk) {
      float2 a = *(const float2*)&As[kk][2 * ty];
      float2 b = *(const float2*)&Bs[kk][2 * tx];
      acc00 += a.x * b.x; acc01 += a.x * b.y;
      acc10 += a.y * b.x; acc11 += a.y * b.y;
    }
    __syncthreads();
  }
  int m = m0 + 2 * ty, n = n0 + 2 * tx;
  if (n < N) {
    out[(size_t)m * N + n] = acc00 + bias[n];
    out[(size_t)(m + 1) * N + n] = acc10 + bias[n];
  }
  if (n + 1 < N) {
    out[(size_t)m * N + n + 1] = acc01 + bias[n + 1];
    out[(size_t)(m + 1) * N + n + 1] = acc11 + bias[n + 1];
  }
}

extern "C" void kernel_launch(void* const* d_in, const int* in_sizes, int n_in,
                              void* d_out, int out_size, void* d_ws, size_t ws_size,
                              hipStream_t stream) {
  (void)in_sizes; (void)n_in; (void)out_size; (void)ws_size;
  const float* feat    = (const float*)d_in[0];
  const float4* boxes1 = (const float4*)d_in[1];
  const float4* boxes2 = (const float4*)d_in[2];
  const float* logits1 = (const float*)d_in[3];
  const float* logits2 = (const float*)d_in[4];
  const int* levels1   = (const int*)d_in[5];
  const int* levels2   = (const int*)d_in[6];
  const float* scale1  = (const float*)d_in[7];
  const float* bias1   = (const float*)d_in[8];
  const float* scale2  = (const float*)d_in[9];
  const float* bias2   = (const float*)d_in[10];
  const float* W_cls1  = (const float*)d_in[11];
  const float* b_cls1  = (const float*)d_in[12];
  const float* W_box1  = (const float*)d_in[13];
  const float* b_box1  = (const float*)d_in[14];
  const float* W_cls2  = (const float*)d_in[15];
  const float* b_cls2  = (const float*)d_in[16];

  float* out = (float*)d_out;
  char* w = (char*)d_ws;
  _Float16* featH           = (_Float16*)(w + 0);                // 8,601,600 B used
  unsigned long long* keys  = (unsigned long long*)(w + 17203200);
  float4* nbox              = (float4*)(w + 17252352);
  float* area               = (float*)(w + 17348352);
  int* rank                 = (int*)(w + 17372352);
  float4* sboxes            = (float4*)(w + 17396352);
  float* sarea              = (float*)(w + 17492352);
  int* sorig                = (int*)(w + 17516352);
  unsigned* mask            = (unsigned*)(w + 17540352);
  int* keep                 = (int*)(w + 22148352);
  float* x1w                = (float*)(w + 22150400);
  float* x2w                = (float*)(w + 24247552);
  // bilin tables alias the (dead-by-then) mask region
  float4* bilinW            = (float4*)(w + 17540352);           // 1,605,632 B
  int4* bilinA              = (int4*)(w + 19145984);             // 1,605,632 B (< keep @22148352)

  k_transpose<<<dim3(132, 32), 256, 0, stream>>>(feat, featH, out + OFF_FEAT);
  k_prep<<<24, 256, 0, stream>>>(boxes1, boxes2, logits1, logits2, levels1, levels2,
                                 nbox, area, keys, rank);
  k_rank<<<dim3(24, 6), 256, 0, stream>>>(keys, rank);
  k_scatter<<<24, 256, 0, stream>>>(nbox, area, rank, sboxes, sarea, sorig);
  k_mask<<<1500, 192, 0, stream>>>(sboxes, sarea, mask);
  k_scan<<<1, 256, 0, stream>>>(mask, sorig, keep);
  k_bilin<<<512, 256, 0, stream>>>(keep, boxes1, boxes2,
                                   (float4*)(out + OFF_PROP), bilinW, bilinA);
  k_roi<<<16384, 256, 0, stream>>>(featH, bilinW, bilinA,
                                   scale1, bias1, scale2, bias2,
                                   out + OFF_BF1, out + OFF_BF2, x1w, x2w);
  k_gemm<<<dim3(16, 10, 3), 256, 0, stream>>>(x1w, x2w, W_cls1, b_cls1, W_box1, b_box1,
                                              W_cls2, b_cls2,
                                              out + OFF_S1, out + OFF_D1, out + OFF_S2);
}

// Round 11
// 471.399 us; speedup vs baseline: 1.1876x; 1.0089x over previous
//
#include <hip/hip_runtime.h>

#define FHH 50
#define FWW 84
#define HW 4200
#define NBOX 6000
#define NPAD 6144
#define KKEEP 512
#define WSTRIDE 192   // mask row stride in words (188 used)

typedef float f32x2 __attribute__((ext_vector_type(2)));
typedef float f32x4v __attribute__((ext_vector_type(4)));
typedef _Float16 f16x8 __attribute__((ext_vector_type(8)));
typedef _Float16 f16x4 __attribute__((ext_vector_type(4)));
typedef _Float16 f16x2 __attribute__((ext_vector_type(2)));

// output offsets (elements, f32)
#define OFF_BF1  0ULL
#define OFF_BF2  102760448ULL
#define OFF_S1   205520896ULL
#define OFF_S2   205562368ULL
#define OFF_D1   205603840ULL
#define OFF_PROP 205767680ULL
#define OFF_FEAT 205769728ULL

// ---------------- feat transpose [C][H][W] -> [H*W][C] fp16, plus feat copy ----------------
__global__ __launch_bounds__(256) void k_transpose(const float* __restrict__ feat,
                                                   _Float16* __restrict__ featH,
                                                   float* __restrict__ out_feat) {
  __shared__ float t[32][33];
  int hw0 = blockIdx.x * 32;
  int c0  = blockIdx.y * 32;
  int tx = threadIdx.x & 31, ty = threadIdx.x >> 5; // ty 0..7
#pragma unroll
  for (int p = 0; p < 4; ++p) {
    int c = c0 + ty + p * 8;
    int hw = hw0 + tx;
    if (hw < HW) {
      float v = feat[(size_t)c * HW + hw];
      t[ty + p * 8][tx] = v;
      __builtin_nontemporal_store(v, &out_feat[(size_t)c * HW + hw]);
    }
  }
  __syncthreads();
#pragma unroll
  for (int p = 0; p < 4; ++p) {
    int hw = hw0 + ty + p * 8;
    int c = c0 + tx;
    if (hw < HW) featH[((size_t)hw << 10) + c] = (_Float16)t[tx][ty + p * 8];
  }
}

// ---------------- NMS prep: clip, offset, area, sort keys ----------------
__global__ __launch_bounds__(256) void k_prep(const float4* __restrict__ boxes1,
                                              const float4* __restrict__ boxes2,
                                              const float* __restrict__ logits1,
                                              const float* __restrict__ logits2,
                                              const int* __restrict__ levels1,
                                              const int* __restrict__ levels2,
                                              float4* __restrict__ nbox,
                                              float* __restrict__ area,
                                              unsigned long long* __restrict__ keys,
                                              int* __restrict__ rank) {
  int i = blockIdx.x * 256 + threadIdx.x;
  if (i >= NPAD) return;
  if (i >= NBOX) { keys[i] = 0ULL; return; }
  rank[i] = 0;
  float4 b; float sc; int lv;
  if (i < 3000) { b = boxes1[i]; sc = logits1[i]; lv = levels1[i]; }
  else          { b = boxes2[i - 3000]; sc = logits2[i - 3000]; lv = levels2[i - 3000]; }
  // clip (exact: min/max only)
  float x0 = fminf(fmaxf(b.x, 0.f), 1344.f);
  float y0 = fminf(fmaxf(b.y, 0.f), 800.f);
  float x1 = fminf(fmaxf(b.z, 0.f), 1344.f);
  float y1 = fminf(fmaxf(b.w, 0.f), 800.f);
  float off = __fmul_rn((float)lv, 1345.0f);
  x0 = __fadd_rn(x0, off); y0 = __fadd_rn(y0, off);
  x1 = __fadd_rn(x1, off); y1 = __fadd_rn(y1, off);
  nbox[i] = make_float4(x0, y0, x1, y1);
  area[i] = __fmul_rn(__fsub_rn(x1, x0), __fsub_rn(y1, y0));
  unsigned u = __float_as_uint(sc);
  u = (u & 0x80000000u) ? ~u : (u | 0x80000000u);   // order-preserving transform
  keys[i] = ((unsigned long long)u << 32) | (unsigned)(0xFFFFFFFFu - (unsigned)i);
}

// ---------------- rank = #{j : key_j > key_i}  (counting sort, stable desc) ----------------
__global__ __launch_bounds__(256) void k_rank(const unsigned long long* __restrict__ keys,
                                              int* __restrict__ rank) {
  __shared__ unsigned long long ks[1024];
  int jb = blockIdx.y;
  for (int t = threadIdx.x; t < 1024; t += 256) ks[t] = keys[jb * 1024 + t];
  __syncthreads();
  int i = blockIdx.x * 256 + threadIdx.x;
  if (i >= NBOX) return;
  unsigned long long ki = keys[i];
  int c = 0;
  for (int j = 0; j < 1024; ++j) c += (ks[j] > ki) ? 1 : 0;
  if (c) atomicAdd(&rank[i], c);
}

__global__ __launch_bounds__(256) void k_scatter(const float4* __restrict__ nbox,
                                                 const float* __restrict__ area,
                                                 const int* __restrict__ rank,
                                                 float4* __restrict__ sboxes,
                                                 float* __restrict__ sarea,
                                                 int* __restrict__ sorig) {
  int i = blockIdx.x * 256 + threadIdx.x;
  if (i >= NBOX) return;
  int r = rank[i];
  sboxes[r] = nbox[i];
  sarea[r] = area[i];
  sorig[r] = i;
}

// ---------------- suppression bitmask ----------------
__global__ __launch_bounds__(192) void k_mask(const float4* __restrict__ sboxes,
                                              const float* __restrict__ sarea,
                                              unsigned* __restrict__ mask) {
  int i0 = blockIdx.x * 4;
  int w = threadIdx.x;  // 0..191
  float4 b0 = sboxes[i0 + 0], b1 = sboxes[i0 + 1], b2 = sboxes[i0 + 2], b3 = sboxes[i0 + 3];
  float a0 = sarea[i0 + 0], a1 = sarea[i0 + 1], a2 = sarea[i0 + 2], a3 = sarea[i0 + 3];
  unsigned m0 = 0, m1 = 0, m2 = 0, m3 = 0;
  int jbase = w * 32;
  for (int bb = 0; bb < 32; ++bb) {
    int j = jbase + bb;
    if (j >= NBOX) break;
    float4 bj = sboxes[j];
    float aj = sarea[j];
#define IOU_BIT(BR, AR, MR)                                                          \
    {                                                                                \
      float ix0 = fmaxf(BR.x, bj.x), iy0 = fmaxf(BR.y, bj.y);                        \
      float ix1 = fminf(BR.z, bj.z), iy1 = fminf(BR.w, bj.w);                        \
      float iw = fmaxf(__fsub_rn(ix1, ix0), 0.f), ih = fmaxf(__fsub_rn(iy1, iy0), 0.f); \
      float inter = __fmul_rn(iw, ih);                                               \
      float den = __fadd_rn(__fsub_rn(__fadd_rn(AR, aj), inter), 1e-9f);             \
      float iou = __fdiv_rn(inter, den);                                             \
      if (iou > 0.7f) MR |= (1u << bb);                                              \
    }
    IOU_BIT(b0, a0, m0) IOU_BIT(b1, a1, m1) IOU_BIT(b2, a2, m2) IOU_BIT(b3, a3, m3)
#undef IOU_BIT
  }
  mask[(size_t)(i0 + 0) * WSTRIDE + w] = m0;
  mask[(size_t)(i0 + 1) * WSTRIDE + w] = m1;
  mask[(size_t)(i0 + 2) * WSTRIDE + w] = m2;
  mask[(size_t)(i0 + 3) * WSTRIDE + w] = m3;
}

// ---------------- sequential scan, rem bitmap in wave-0 registers ----------------
#define SCAN_CH 64
__global__ __launch_bounds__(256) void k_scan(const unsigned* __restrict__ mask,
                                              const int* __restrict__ sorig,
                                              int* __restrict__ keep) {
  __shared__ unsigned srows[2][SCAN_CH * WSTRIDE];  // 2 x 48 KiB
  __shared__ int s_sorig[2][SCAN_CH];
  __shared__ int s_done, s_kept;
  int tid = threadIdx.x;
  if (tid == 0) { s_done = 0; s_kept = 0; }
  // stage batch 0 with all threads
  for (int idx = tid; idx < SCAN_CH * WSTRIDE; idx += 256) srows[0][idx] = mask[idx];
  if (tid < SCAN_CH) s_sorig[0][tid] = sorig[tid];
  __syncthreads();
  unsigned r0 = 0, r1 = 0, r2 = 0;   // rem words: lane, 64+lane, 128+lane
  int lane = tid;
  int kept = 0;
  for (int g = 0; g < 94; ++g) {
    int cur = g & 1, nxt = cur ^ 1;
    if (tid >= 64) {
      int gn = g + 1;
      if (gn < 94) {
        size_t gbase = (size_t)gn * SCAN_CH * WSTRIDE;
        for (int idx = tid - 64; idx < SCAN_CH * WSTRIDE; idx += 192) {
          size_t gi = gbase + idx;
          srows[nxt][idx] = (gi < (size_t)NBOX * WSTRIDE) ? mask[gi] : 0u;
        }
        if (tid - 64 < SCAN_CH) {
          int i2 = gn * SCAN_CH + (tid - 64);
          s_sorig[nxt][tid - 64] = (i2 < NBOX) ? sorig[i2] : 0;
        }
      }
    } else {
      int base = g * SCAN_CH;
      int nrows = min(SCAN_CH, NBOX - base);
      const unsigned* sb = srows[cur];
      unsigned p0 = sb[lane], p1 = sb[64 + lane], p2 = sb[128 + lane];
      for (int rr = 0; rr < nrows; ++rr) {
        unsigned c0v = p0, c1v = p1, c2v = p2;
        int rn = (rr + 1 < nrows) ? rr + 1 : rr;
        p0 = sb[rn * WSTRIDE + lane];
        p1 = sb[rn * WSTRIDE + 64 + lane];
        p2 = sb[rn * WSTRIDE + 128 + lane];
        int i = base + rr;
        int w = i >> 5, b = i & 31;
        int wl = w & 63, wc = w >> 6;
        unsigned rsel = (wc == 0) ? r0 : ((wc == 1) ? r1 : r2);
        unsigned rw = __shfl(rsel, wl);
        if (!((rw >> b) & 1u)) {
          r0 |= c0v; r1 |= c1v; r2 |= c2v;
          if (lane == 0) keep[kept] = s_sorig[cur][rr];
          kept++;
          if (kept >= KKEEP) break;
        }
      }
      if (lane == 0) { s_kept = kept; if (kept >= KKEEP) s_done = 1; }
    }
    __syncthreads();
    if (s_done) break;
  }
  __syncthreads();
  int fk = s_kept;
  for (int k = fk + tid; k < KKEEP; k += 256) keep[k] = 0;  // ref pads with idx 0
}

// ---------------- proposals + per-(roi,bin) bilinear weights/addresses ----------------
__global__ __launch_bounds__(256) void k_bilin(const int* __restrict__ keep,
                                               const float4* __restrict__ boxes1,
                                               const float4* __restrict__ boxes2,
                                               float4* __restrict__ prop,
                                               float4* __restrict__ bilinW,
                                               int4* __restrict__ bilinA) {
  int r = blockIdx.x;
  __shared__ float4 spb;
  if (threadIdx.x == 0) {
    int o = keep[r];
    float4 b = (o < 3000) ? boxes1[o] : boxes2[o - 3000];
    float4 p = make_float4(fminf(fmaxf(b.x, 0.f), 1344.f),
                           fminf(fmaxf(b.y, 0.f), 800.f),
                           fminf(fmaxf(b.z, 0.f), 1344.f),
                           fminf(fmaxf(b.w, 0.f), 800.f));
    prop[r] = p;
    spb = p;
  }
  __syncthreads();
  int bin = threadIdx.x;
  if (bin >= 196) return;
  float4 pb = spb;
  const float ss = 0.0625f;
  float x0s = pb.x * ss - 0.5f, y0s = pb.y * ss - 0.5f;
  float bw = (pb.z * ss - 0.5f - x0s) / 14.0f;
  float bh = (pb.w * ss - 0.5f - y0s) / 14.0f;
  int py = bin / 14, px = bin - py * 14;
  float xs = x0s + ((float)px + 0.5f) * bw;
  float ys = y0s + ((float)py + 0.5f) * bh;
  float xf = floorf(xs), yf = floorf(ys);
  float lx = xs - xf, ly = ys - yf;
  int ix = (int)xf, iy = (int)yf;
  int x0c = min(max(ix, 0), FWW - 1), x1c = min(max(ix + 1, 0), FWW - 1);
  int y0c = min(max(iy, 0), FHH - 1), y1c = min(max(iy + 1, 0), FHH - 1);
  float wy0 = 1.f - ly, wx0 = 1.f - lx;
  bilinW[r * 196 + bin] = make_float4(wy0 * wx0, wy0 * lx, ly * wx0, ly * lx);
  bilinA[r * 196 + bin] = make_int4((y0c * FWW + x0c) << 10, (y0c * FWW + x1c) << 10,
                                    (y1c * FWW + x0c) << 10, (y1c * FWW + x1c) << 10);
}

// ---------------- ROIAlign + both affine heads + fused mean -> x1,x2 ----------------
// Round-11: 64-channel chunks, lane loads f16x8 (16B) -> gather ADDRESS count
// halved (103M -> 51M); tile is [bin][72] channel-fast -> one ds_write_b128
// per bin per lane (was 4x ds_write_b16), ~2-way banks (free).
__global__ __launch_bounds__(256) void k_roi(const _Float16* __restrict__ featH,
                                             const float4* __restrict__ bilinW,
                                             const int4* __restrict__ bilinA,
                                             const float* __restrict__ scale1,
                                             const float* __restrict__ bias1,
                                             const float* __restrict__ scale2,
                                             const float* __restrict__ bias2,
                                             float* __restrict__ bf1,
                                             float* __restrict__ bf2,
                                             float* __restrict__ x1w,
                                             float* __restrict__ x2w) {
  __shared__ _Float16 tile[196 * 72];   // 28224 B, [bin][72] (64 ch + pad)
  __shared__ float part2f[4 * 64];
  __shared__ float sc1[64], bi1[64], sc2[64], bi2[64];
  int bid = blockIdx.x;
  int r = bid & 511;
  int c0 = (bid >> 9) * 64;
  int tid = threadIdx.x;
  int l8 = tid & 7, bg = tid >> 3;       // channel-octet (8), bin-group (32)
  if (tid < 64) {
    sc1[tid] = scale1[c0 + tid]; bi1[tid] = bias1[c0 + tid];
    sc2[tid] = scale2[c0 + tid]; bi2[tid] = bias2[c0 + tid];
  }
  const _Float16* fTb = featH + c0 + l8 * 8;
  const float4* bW = bilinW + r * 196;
  const int4* bA = bilinA + r * 196;
  float acc[8];
#pragma unroll
  for (int j = 0; j < 8; ++j) acc[j] = 0.f;

#define ROI_BODY(BB)                                                              \
  {                                                                               \
    float4 w = bW[BB]; int4 a = bA[BB];                                           \
    f16x8 g00 = *(const f16x8*)(fTb + a.x);                                       \
    f16x8 g01 = *(const f16x8*)(fTb + a.y);                                       \
    f16x8 g10 = *(const f16x8*)(fTb + a.z);                                       \
    f16x8 g11 = *(const f16x8*)(fTb + a.w);                                       \
    f16x8 vv;                                                                     \
    _Pragma("unroll")                                                             \
    for (int j = 0; j < 8; ++j) {                                                 \
      float v = (float)g00[j] * w.x + (float)g01[j] * w.y                         \
              + (float)g10[j] * w.z + (float)g11[j] * w.w;                        \
      acc[j] += v; vv[j] = (_Float16)v;                                           \
    }                                                                             \
    *(f16x8*)(&tile[(BB) * 72 + l8 * 8]) = vv;                                    \
  }

  int bb = bg;
#pragma unroll
  for (int i = 0; i < 6; ++i, bb += 32) ROI_BODY(bb)
  if (bg < 4) ROI_BODY(192 + bg)
#undef ROI_BODY

  // reduce acc over the 8 bin-groups within each wave (flip tid bits 3,4,5)
#pragma unroll
  for (int j = 0; j < 8; ++j) {
    acc[j] += __shfl_xor(acc[j], 8);
    acc[j] += __shfl_xor(acc[j], 16);
    acc[j] += __shfl_xor(acc[j], 32);
  }
  if ((tid & 63) < 8) {
    int wv = tid >> 6;
#pragma unroll
    for (int j = 0; j < 8; ++j) part2f[wv * 64 + l8 * 8 + j] = acc[j];
  }
  __syncthreads();
  if (tid < 64) {
    float m = ((part2f[tid] + part2f[64 + tid]) + part2f[128 + tid]) + part2f[192 + tid];
    m = m / 196.0f;
    x1w[((size_t)r << 10) + c0 + tid] = m * sc1[tid] + bi1[tid];
    x2w[((size_t)r << 10) + c0 + tid] = m * sc2[tid] + bi2[tid];
  }
  size_t ob = ((size_t)((r << 10) + c0)) * 196;
  float* b1p = bf1 + ob;
  float* b2p = bf2 + ob;
  // 3136 quads (64 ch x 49 quads); quad q -> channel cl, bins pos..pos+3
  for (int it = 0; it < 13; ++it) {
    int q = tid + it * 256;
    if (q < 3136) {
      int cl = q / 49;
      int pos = (q - cl * 49) * 4;
      float v0 = (float)tile[(pos + 0) * 72 + cl];
      float v1 = (float)tile[(pos + 1) * 72 + cl];
      float v2 = (float)tile[(pos + 2) * 72 + cl];
      float v3 = (float)tile[(pos + 3) * 72 + cl];
      float s1v = sc1[cl], b1v = bi1[cl], s2v = sc2[cl], b2v = bi2[cl];
      f32x4v o1 = { v0 * s1v + b1v, v1 * s1v + b1v, v2 * s1v + b1v, v3 * s1v + b1v };
      f32x4v o2 = { v0 * s2v + b2v, v1 * s2v + b2v, v2 * s2v + b2v, v3 * s2v + b2v };
      __builtin_nontemporal_store(o1, (f32x4v*)(b1p + 4 * q));
      __builtin_nontemporal_store(o2, (f32x4v*)(b2p + 4 * q));
    }
  }
}

// ---------------- small GEMMs: s1 = x1@Wc1+bc1, d1 = x1@Wb1+bb1, s2 = x2@Wc2+bc2 ----------------
__global__ __launch_bounds__(256) void k_gemm(const float* __restrict__ x1,
                                              const float* __restrict__ x2,
                                              const float* __restrict__ Wc1, const float* __restrict__ bc1,
                                              const float* __restrict__ Wb1, const float* __restrict__ bb1,
                                              const float* __restrict__ Wc2, const float* __restrict__ bc2,
                                              float* __restrict__ s1, float* __restrict__ d1,
                                              float* __restrict__ s2) {
  int z = blockIdx.z;
  const float* A; const float* W; const float* bias; float* out; int N;
  if (z == 0)      { A = x1; W = Wc1; bias = bc1; out = s1; N = 81; }
  else if (z == 1) { A = x1; W = Wb1; bias = bb1; out = d1; N = 320; }
  else             { A = x2; W = Wc2; bias = bc2; out = s2; N = 81; }
  int n0 = blockIdx.y * 32;
  if (n0 >= N) return;
  int m0 = blockIdx.x * 32;
  __shared__ float As[32][34];
  __shared__ float Bs[32][34];
  int tid = threadIdx.x;
  int tx = tid & 15, ty = tid >> 4;
  float acc00 = 0, acc01 = 0, acc10 = 0, acc11 = 0;
  for (int k0 = 0; k0 < 1024; k0 += 32) {
    int mm = tid >> 3, g = tid & 7;
    float4 av = *(const float4*)(A + (size_t)(m0 + mm) * 1024 + k0 + g * 4);
    As[g * 4 + 0][mm] = av.x; As[g * 4 + 1][mm] = av.y;
    As[g * 4 + 2][mm] = av.z; As[g * 4 + 3][mm] = av.w;
    int nn = tid & 31, kh = tid >> 5;
#pragma unroll
    for (int qq = 0; qq < 4; ++qq) {
      int kk = kh + 8 * qq;
      int n = n0 + nn;
      Bs[kk][nn] = (n < N) ? W[(size_t)(k0 + kk) * N + n] : 0.f;
    }
    __syncthreads();
#pragma unroll
    for (int kk = 0; kk < 32; ++kk) {
      float2 a = *(const float2*)&As[kk][2 * ty];
      float2 b = *(const float2*)&Bs[kk][2 * tx];
      acc00 += a.x * b.x; acc01 += a.x * b.y;
      acc10 += a.y * b.x; acc11 += a.y * b.y;
    }
    __syncthreads();
  }
  int m = m0 + 2 * ty, n = n0 + 2 * tx;
  if (n < N) {
    out[(size_t)m * N + n] = acc00 + bias[n];
    out[(size_t)(m + 1) * N + n] = acc10 + bias[n];
  }
  if (n + 1 < N) {
    out[(size_t)m * N + n + 1] = acc01 + bias[n + 1];
    out[(size_t)(m + 1) * N + n + 1] = acc11 + bias[n + 1];
  }
}

extern "C" void kernel_launch(void* const* d_in, const int* in_sizes, int n_in,
                              void* d_out, int out_size, void* d_ws, size_t ws_size,
                              hipStream_t stream) {
  (void)in_sizes; (void)n_in; (void)out_size; (void)ws_size;
  const float* feat    = (const float*)d_in[0];
  const float4* boxes1 = (const float4*)d_in[1];
  const float4* boxes2 = (const float4*)d_in[2];
  const float* logits1 = (const float*)d_in[3];
  const float* logits2 = (const float*)d_in[4];
  const int* levels1   = (const int*)d_in[5];
  const int* levels2   = (const int*)d_in[6];
  const float* scale1  = (const float*)d_in[7];
  const float* bias1   = (const float*)d_in[8];
  const float* scale2  = (const float*)d_in[9];
  const float* bias2   = (const float*)d_in[10];
  const float* W_cls1  = (const float*)d_in[11];
  const float* b_cls1  = (const float*)d_in[12];
  const float* W_box1  = (const float*)d_in[13];
  const float* b_box1  = (const float*)d_in[14];
  const float* W_cls2  = (const float*)d_in[15];
  const float* b_cls2  = (const float*)d_in[16];

  float* out = (float*)d_out;
  char* w = (char*)d_ws;
  _Float16* featH           = (_Float16*)(w + 0);                // 8,601,600 B used
  unsigned long long* keys  = (unsigned long long*)(w + 17203200);
  float4* nbox              = (float4*)(w + 17252352);
  float* area               = (float*)(w + 17348352);
  int* rank                 = (int*)(w + 17372352);
  float4* sboxes            = (float4*)(w + 17396352);
  float* sarea              = (float*)(w + 17492352);
  int* sorig                = (int*)(w + 17516352);
  unsigned* mask            = (unsigned*)(w + 17540352);
  int* keep                 = (int*)(w + 22148352);
  float* x1w                = (float*)(w + 22150400);
  float* x2w                = (float*)(w + 24247552);
  // bilin tables alias the (dead-by-then) mask region
  float4* bilinW            = (float4*)(w + 17540352);           // 1,605,632 B
  int4* bilinA              = (int4*)(w + 19145984);             // 1,605,632 B (< keep @22148352)

  k_transpose<<<dim3(132, 32), 256, 0, stream>>>(feat, featH, out + OFF_FEAT);
  k_prep<<<24, 256, 0, stream>>>(boxes1, boxes2, logits1, logits2, levels1, levels2,
                                 nbox, area, keys, rank);
  k_rank<<<dim3(24, 6), 256, 0, stream>>>(keys, rank);
  k_scatter<<<24, 256, 0, stream>>>(nbox, area, rank, sboxes, sarea, sorig);
  k_mask<<<1500, 192, 0, stream>>>(sboxes, sarea, mask);
  k_scan<<<1, 256, 0, stream>>>(mask, sorig, keep);
  k_bilin<<<512, 256, 0, stream>>>(keep, boxes1, boxes2,
                                   (float4*)(out + OFF_PROP), bilinW, bilinA);
  k_roi<<<8192, 256, 0, stream>>>(featH, bilinW, bilinA,
                                  scale1, bias1, scale2, bias2,
                                  out + OFF_BF1, out + OFF_BF2, x1w, x2w);
  k_gemm<<<dim3(16, 10, 3), 256, 0, stream>>>(x1w, x2w, W_cls1, b_cls1, W_box1, b_box1,
                                              W_cls2, b_cls2,
                                              out + OFF_S1, out + OFF_D1, out + OFF_S2);
}